// Round 5
// baseline (959.823 us; speedup 1.0000x reference)
//
#include <hip/hip_runtime.h>
#include <math.h>

typedef unsigned short u16;
typedef __attribute__((ext_vector_type(8))) short bf16x8;
typedef __attribute__((ext_vector_type(4))) float f32x4;

__device__ __forceinline__ u16 f2b(float f) {
    union { float f; unsigned u; } v; v.f = f;
    unsigned r = (v.u + 0x7FFF + ((v.u >> 16) & 1)) >> 16;
    return (u16)r;
}
__device__ __forceinline__ unsigned pack2(float a, float b) {
    return (unsigned)f2b(a) | ((unsigned)f2b(b) << 16);
}
__device__ __forceinline__ f32x4 vmul(f32x4 a, float s) {
    f32x4 r; r[0]=a[0]*s; r[1]=a[1]*s; r[2]=a[2]*s; r[3]=a[3]*s; return r;
}
__device__ __forceinline__ f32x4 vmad(f32x4 a, float s, f32x4 c) {
    c[0]=fmaf(a[0],s,c[0]); c[1]=fmaf(a[1],s,c[1]);
    c[2]=fmaf(a[2],s,c[2]); c[3]=fmaf(a[3],s,c[3]); return c;
}

// ---- weight prep: src fp32 [Nsrc][64][3][3] -> dst bf16 [Npad][576], K = ktap*64 + c ----
__global__ void prep_w_kernel(const float* __restrict__ src, u16* __restrict__ dst,
                              int Nsrc, int Npad) {
    int idx = blockIdx.x * 256 + threadIdx.x;
    if (idx >= Npad * 576) return;
    int n = idx / 576;
    int K = idx - n * 576;
    int ktap = K >> 6;
    int c = K & 63;
    float v = (n < Nsrc) ? src[((size_t)n * 64 + c) * 9 + ktap] : 0.f;
    dst[idx] = f2b(v);
}

// ---- NCHW -> NHWC transpose: x[b][c][h][w] -> xh[b][(h*W+w)*64 + c] ----
template<int H, int W>
__global__ __launch_bounds__(256) void nchw2nhwc(const float* __restrict__ src,
                                                 float* __restrict__ dst) {
    const int SEG = W / 64, HW = H * W;
    int blk = blockIdx.x;                  // B*H*SEG
    int b = blk / (H * SEG);
    int r = blk - b * (H * SEG);
    int h = r / SEG;
    int x0 = (r - h * SEG) * 64;
    int t = threadIdx.x;
    __shared__ float lds[64][65];
    const float* sb = src + (size_t)b * 64 * HW + (size_t)h * W + x0;
    int px = t & 63, cg = t >> 6;
#pragma unroll
    for (int i = 0; i < 16; ++i) {
        int c = cg * 16 + i;
        lds[c][px] = sb[(size_t)c * HW + px];
    }
    __syncthreads();
    float* db = dst + ((size_t)b * HW + (size_t)h * W + x0) * 64;
    int c = t & 63, pg = t >> 6;
#pragma unroll
    for (int i = 0; i < 16; ++i) {
        int p = pg * 16 + i;
        db[(size_t)p * 64 + c] = lds[c][p];
    }
}

// ---- bilinear 2x upsample, NCHW (192^2) in -> NHWC (384^2) out ----
__global__ __launch_bounds__(256) void upsample_nhwc(const float* __restrict__ src,
                                                     float* __restrict__ dst) {
    const int Hh = 192, Wh = 192, H = 384, W = 384;
    int ox0 = blockIdx.x * 32;
    int oy  = blockIdx.y;
    int b   = blockIdx.z;
    int t = threadIdx.x;
    int iy  = oy >> 1;
    int oy2 = (oy & 1) ? min(iy + 1, Hh - 1) : max(iy - 1, 0);
    int ix0m1 = ox0 / 2 - 1;
    __shared__ float lds[2][64][19];
    const float* sb = src + (size_t)b * 64 * Hh * Wh;
    for (int idx = t; idx < 2 * 64 * 18; idx += 256) {
        int r2 = idx / (64 * 18);
        int rem = idx - r2 * (64 * 18);
        int c = rem / 18;
        int p = rem - c * 18;
        int gx = min(max(ix0m1 + p, 0), Wh - 1);
        int gy = r2 ? oy2 : iy;
        lds[r2][c][p] = sb[((size_t)c * Hh + gy) * Wh + gx];
    }
    __syncthreads();
    int c = t & 63, j = t >> 6;
    float* db = dst + ((size_t)b * H * W + (size_t)oy * W + ox0) * 64;
#pragma unroll
    for (int ii = 0; ii < 8; ++ii) {
        int opx = j * 8 + ii;
        int ox = ox0 + opx;
        int ix = ox >> 1;
        int oxn = (ox & 1) ? min(ix + 1, Wh - 1) : max(ix - 1, 0);
        int il = ix - ix0m1;
        int ol = oxn - ix0m1;
        float cc = lds[0][c][il], cn = lds[0][c][ol];
        float nc = lds[1][c][il], nn = lds[1][c][ol];
        db[(size_t)opx * 64 + c] = 0.5625f * cc + 0.1875f * (cn + nc) + 0.0625f * nn;
    }
}

// ---- conv3x3 offset conv, register-A MFMA, NHWC input, zero-pad ----
// wave = 16 px of one row x 32(27) oc; lane(m16,quad): A[m16][quad*8+j] built in regs.
template<int H, int W>
__global__ __launch_bounds__(256) void conv_off_rA(
    const float* __restrict__ srcT,  // B x HW x 64 (NHWC)
    const u16*  __restrict__ wb,     // 32 x 576 bf16
    const float* __restrict__ bias,  // 27
    float* __restrict__ dst)         // B x 27 x H x W
{
    const int HW = H * W, SEGS = W / 16;
    int t = threadIdx.x;
    int wv = t >> 6, m16 = t & 15, quad = (t >> 4) & 3;
    int seg = blockIdx.x * 4 + wv;
    int b = seg / (H * SEGS);
    int r = seg - b * (H * SEGS);
    int h = r / SEGS;
    int x0 = (r - h * SEGS) * 16;

    const float* sb = srcT + (size_t)b * HW * 64;
    f32x4 acc[2] = {{0.f,0.f,0.f,0.f},{0.f,0.f,0.f,0.f}};

    int ki = 0, kj = 0;
#pragma unroll 1
    for (int k = 0; k < 9; ++k) {
        int yy = h - 1 + ki;
        int xx = x0 + m16 - 1 + kj;
        float fl = (yy >= 0 && yy < H && xx >= 0 && xx < W) ? 1.f : 0.f;
        int yc = min(max(yy, 0), H - 1);
        int xc = min(max(xx, 0), W - 1);
        const float* base = sb + (size_t)(yc * W + xc) * 64;
#pragma unroll
        for (int cb = 0; cb < 2; ++cb) {
            int co = cb * 32 + quad * 8;
            const f32x4* q = (const f32x4*)(base + co);
            f32x4 s0 = vmul(q[0], fl);
            f32x4 s1 = vmul(q[1], fl);
            union { unsigned u[4]; bf16x8 v; } A;
            A.u[0] = pack2(s0[0], s0[1]); A.u[1] = pack2(s0[2], s0[3]);
            A.u[2] = pack2(s1[0], s1[1]); A.u[3] = pack2(s1[2], s1[3]);
            const u16* wk = wb + k * 64 + co;
#pragma unroll
            for (int g = 0; g < 2; ++g) {
                bf16x8 bf = *(const bf16x8*)(wk + (size_t)(g * 16 + m16) * 576);
                acc[g] = __builtin_amdgcn_mfma_f32_16x16x32_bf16(A.v, bf, acc[g], 0, 0, 0);
            }
        }
        if (++kj == 3) { kj = 0; ++ki; }
    }

    int xs = x0 + quad * 4;
    float* dbase = dst + (size_t)b * 27 * HW + (size_t)h * W + xs;
    {
        f32x4 v = acc[0]; float bz = bias[m16];
        v[0] += bz; v[1] += bz; v[2] += bz; v[3] += bz;
        *(f32x4*)(dbase + (size_t)m16 * HW) = v;
    }
    if (m16 < 11) {
        f32x4 v = acc[1]; float bz = bias[16 + m16];
        v[0] += bz; v[1] += bz; v[2] += bz; v[3] += bz;
        *(f32x4*)(dbase + (size_t)(16 + m16) * HW) = v;
    }
}

// ---- deformable conv v2, register-A MFMA, NHWC input, no LDS, no barriers ----
template<int H, int W, bool ADD_RES>
__global__ __launch_bounds__(256) void dcn_rA(
    const float* __restrict__ srcT,  // B x HW x 64 (NHWC)
    const float* __restrict__ off,   // B x 27 x H x W
    const u16*  __restrict__ wb,     // 64 x 576 bf16
    const float* __restrict__ bias,  // 64
    const float* __restrict__ res,   // B x 64 x H/2 x W/2 (if ADD_RES)
    float* __restrict__ dst)         // B x 64 x H x W
{
    const int HW = H * W, SEGS = W / 16;
    int t = threadIdx.x;
    int wv = t >> 6, m16 = t & 15, quad = (t >> 4) & 3;
    int seg = blockIdx.x * 4 + wv;
    int b = seg / (H * SEGS);
    int r = seg - b * (H * SEGS);
    int h = r / SEGS;
    int x0 = (r - h * SEGS) * 16;

    const float* sb = srcT + (size_t)b * HW * 64;
    const float* offp = off + (size_t)b * 27 * HW + (size_t)h * W + x0 + m16;

    f32x4 acc[4] = {{0.f,0.f,0.f,0.f},{0.f,0.f,0.f,0.f},
                    {0.f,0.f,0.f,0.f},{0.f,0.f,0.f,0.f}};

    int ki = 0, kj = 0;
#pragma unroll 1
    for (int k = 0; k < 9; ++k) {
        float dy = offp[(size_t)(2 * k) * HW];
        float dx = offp[(size_t)(2 * k + 1) * HW];
        float mm = 1.f / (1.f + __expf(-offp[(size_t)(18 + k) * HW]));

        float yf = (float)(h - 1 + ki) + dy;
        float xf = (float)(x0 + m16 - 1 + kj) + dx;
        float y0f = floorf(yf), x0f = floorf(xf);
        float wy = yf - y0f, wx = xf - x0f;
        int yi = (int)y0f, xi = (int)x0f;
        float vy0 = (yi >= 0 && yi < H) ? 1.f : 0.f;
        float vy1 = (yi + 1 >= 0 && yi + 1 < H) ? 1.f : 0.f;
        float vx0 = (xi >= 0 && xi < W) ? 1.f : 0.f;
        float vx1 = (xi + 1 >= 0 && xi + 1 < W) ? 1.f : 0.f;
        float w00 = (1.f - wy) * (1.f - wx) * vy0 * vx0 * mm;
        float w01 = (1.f - wy) * wx * vy0 * vx1 * mm;
        float w10 = wy * (1.f - wx) * vy1 * vx0 * mm;
        float w11 = wy * wx * vy1 * vx1 * mm;
        int y0c = min(max(yi, 0), H - 1), y1c = min(max(yi + 1, 0), H - 1);
        int x0c = min(max(xi, 0), W - 1), x1c = min(max(xi + 1, 0), W - 1);
        const float* p00 = sb + (size_t)(y0c * W + x0c) * 64;
        const float* p01 = sb + (size_t)(y0c * W + x1c) * 64;
        const float* p10 = sb + (size_t)(y1c * W + x0c) * 64;
        const float* p11 = sb + (size_t)(y1c * W + x1c) * 64;

#pragma unroll
        for (int cb = 0; cb < 2; ++cb) {
            int co = cb * 32 + quad * 8;
            const f32x4* q00 = (const f32x4*)(p00 + co);
            const f32x4* q01 = (const f32x4*)(p01 + co);
            const f32x4* q10 = (const f32x4*)(p10 + co);
            const f32x4* q11 = (const f32x4*)(p11 + co);
            f32x4 s0 = vmul(q00[0], w00);
            s0 = vmad(q01[0], w01, s0);
            s0 = vmad(q10[0], w10, s0);
            s0 = vmad(q11[0], w11, s0);
            f32x4 s1 = vmul(q00[1], w00);
            s1 = vmad(q01[1], w01, s1);
            s1 = vmad(q10[1], w10, s1);
            s1 = vmad(q11[1], w11, s1);
            union { unsigned u[4]; bf16x8 v; } A;
            A.u[0] = pack2(s0[0], s0[1]); A.u[1] = pack2(s0[2], s0[3]);
            A.u[2] = pack2(s1[0], s1[1]); A.u[3] = pack2(s1[2], s1[3]);
            const u16* wk = wb + k * 64 + co;
#pragma unroll
            for (int g = 0; g < 4; ++g) {
                bf16x8 bf = *(const bf16x8*)(wk + (size_t)(g * 16 + m16) * 576);
                acc[g] = __builtin_amdgcn_mfma_f32_16x16x32_bf16(A.v, bf, acc[g], 0, 0, 0);
            }
        }
        if (++kj == 3) { kj = 0; ++ki; }
    }

    // epilogue: bias + ELU (+ upsampled residual) + f32x4 stores (4 px per reg)
    int xs = x0 + quad * 4;
    float* dbase = dst + (size_t)b * 64 * HW + (size_t)h * W + xs;
    const int Hh = H / 2, Wh = W / 2;
    int iy = h >> 1;
    int oyn = (h & 1) ? min(iy + 1, Hh - 1) : max(iy - 1, 0);
    int doy = (oyn - iy) * Wh;
#pragma unroll
    for (int g = 0; g < 4; ++g) {
        int oc = g * 16 + m16;
        f32x4 v = acc[g];
        float bz = bias[oc];
        const float* rp = ADD_RES ? (res + (size_t)(b * 64 + oc) * Hh * Wh + (size_t)iy * Wh)
                                  : (const float*)nullptr;
#pragma unroll
        for (int rg = 0; rg < 4; ++rg) {
            float val = v[rg] + bz;
            val = val > 0.f ? val : (expf(val) - 1.f);
            if (ADD_RES) {
                int xq = xs + rg;
                int ix = xq >> 1;
                int oxn = (xq & 1) ? min(ix + 1, Wh - 1) : max(ix - 1, 0);
                val += 0.5625f * rp[ix] + 0.1875f * (rp[oxn] + rp[doy + ix])
                     + 0.0625f * rp[doy + oxn];
            }
            v[rg] = val;
        }
        *(f32x4*)(dbase + (size_t)oc * HW) = v;
    }
}

// ---------------- conv1x1 residual: 16 oc per thread (no spill) ----------------
__global__ __launch_bounds__(256) void conv1x1_kernel(
    const float* __restrict__ x,   // B x 64 x 192 x 192
    const float* __restrict__ rw,  // 64 x 64
    const float* __restrict__ rb,  // 64
    float* __restrict__ dst)       // B x 64 x 192 x 192
{
    const int HW = 192 * 192;
    int p = blockIdx.x * 256 + threadIdx.x;   // over B*HW (exact)
    int g = blockIdx.y;                       // oc group (wave-uniform)
    int b = p / HW;
    int hw = p - b * HW;
    const float* xb = x + (size_t)b * 64 * HW + hw;

    float acc[16];
#pragma unroll
    for (int o = 0; o < 16; ++o) acc[o] = rb[g * 16 + o];

#pragma unroll 4
    for (int c = 0; c < 64; ++c) {
        float v = xb[(size_t)c * HW];
#pragma unroll
        for (int o = 0; o < 16; ++o)
            acc[o] = fmaf(v, rw[(g * 16 + o) * 64 + c], acc[o]);
    }

    float* db = dst + (size_t)b * 64 * HW + (size_t)g * 16 * HW + hw;
#pragma unroll
    for (int o = 0; o < 16; ++o)
        db[(size_t)o * HW] = acc[o];
}

extern "C" void kernel_launch(void* const* d_in, const int* in_sizes, int n_in,
                              void* d_out, int out_size, void* d_ws, size_t ws_size,
                              hipStream_t stream) {
    const float* x   = (const float*)d_in[0];
    const float* ow1 = (const float*)d_in[1];
    const float* ob1 = (const float*)d_in[2];
    const float* w1  = (const float*)d_in[3];
    const float* b1  = (const float*)d_in[4];
    const float* ow2 = (const float*)d_in[5];
    const float* ob2 = (const float*)d_in[6];
    const float* w2  = (const float*)d_in[7];
    const float* b2  = (const float*)d_in[8];
    const float* rw  = (const float*)d_in[9];
    const float* rbv = (const float*)d_in[10];
    float* out = (float*)d_out;

    // workspace layout (floats) — total 153,280,512 B, same as proven rounds 2-4
    float* ws   = (float*)d_ws;
    float* off1 = ws;                       //  2*27*192*192 = 1,990,656
    float* h1   = off1 + 1990656;           //  2*64*192*192 = 4,718,592
    float* r    = h1   + 4718592;           //  4,718,592
    float* u    = r    + 4718592;           //  2*(384*384)*64 NHWC = 18,874,368
    float* xh   = u;                        //  alias: xh (NHWC x, 4,718,592) dead before u written
    float* off2 = u    + 18874368;          //  2*27*384*384 = 7,962,624
    u16* wb1    = (u16*)(off2 + 7962624);   //  64*576 bf16
    u16* wb2    = wb1 + 64 * 576;
    u16* wboff1 = wb2 + 64 * 576;           //  32*576
    u16* wboff2 = wboff1 + 32 * 576;

    prep_w_kernel<<<(64 * 576 + 255) / 256, 256, 0, stream>>>(w1, wb1, 64, 64);
    prep_w_kernel<<<(64 * 576 + 255) / 256, 256, 0, stream>>>(w2, wb2, 64, 64);
    prep_w_kernel<<<(32 * 576 + 255) / 256, 256, 0, stream>>>(ow1, wboff1, 27, 32);
    prep_w_kernel<<<(32 * 576 + 255) / 256, 256, 0, stream>>>(ow2, wboff2, 27, 32);

    nchw2nhwc<192, 192><<<2 * 192 * 3, 256, 0, stream>>>(x, xh);
    conv_off_rA<192, 192><<<(2 * 192 * 12) / 4, 256, 0, stream>>>(xh, wboff1, ob1, off1);
    conv1x1_kernel<<<dim3(288, 4), 256, 0, stream>>>(x, rw, rbv, r);
    dcn_rA<192, 192, false><<<(2 * 192 * 12) / 4, 256, 0, stream>>>(xh, off1, wb1, b1, nullptr, h1);
    upsample_nhwc<<<dim3(12, 384, 2), 256, 0, stream>>>(h1, u);
    conv_off_rA<384, 384><<<(2 * 384 * 24) / 4, 256, 0, stream>>>(u, wboff2, ob2, off2);
    dcn_rA<384, 384, true><<<(2 * 384 * 24) / 4, 256, 0, stream>>>(u, off2, wb2, b2, r, out);
}

// Round 6
// 462.586 us; speedup vs baseline: 2.0749x; 2.0749x over previous
//
#include <hip/hip_runtime.h>
#include <math.h>

typedef unsigned short u16;
typedef __attribute__((ext_vector_type(8))) short bf16x8;
typedef __attribute__((ext_vector_type(4))) float f32x4;
typedef __attribute__((ext_vector_type(4))) unsigned u32x4;

__device__ __forceinline__ u16 f2b(float f) {
    union { float f; unsigned u; } v; v.f = f;
    unsigned r = (v.u + 0x7FFF + ((v.u >> 16) & 1)) >> 16;
    return (u16)r;
}
__device__ __forceinline__ unsigned pack2(float a, float b) {
    return (unsigned)f2b(a) | ((unsigned)f2b(b) << 16);
}
__device__ __forceinline__ void bpair(unsigned u, float& lo, float& hi) {
    union { unsigned q; float f; } a, b;
    a.q = u << 16; b.q = u & 0xFFFF0000u;
    lo = a.f; hi = b.f;
}

// ---- weight prep into MFMA B-fragment order ----
// dst[((kcb*G + g)*64 + lane)*8 + j] = w[oc = g*16+(lane&15)]
//                                       [c  = (kcb&1)*32+(lane>>4)*8+j][tap = kcb>>1]
// src layout: [oc][64][TS] (TS=9 for 3x3, TS=1 for 1x1). oc>=NOC -> 0.
__global__ void prep_frag(const float* __restrict__ src, u16* __restrict__ dst,
                          int G, int KCB, int NOC, int TS) {
    int idx = blockIdx.x * 256 + threadIdx.x;
    if (idx >= KCB * G * 512) return;
    int j = idx & 7, lane = (idx >> 3) & 63, rest = idx >> 9;
    int g = rest % G, kcb = rest / G;
    int oc = g * 16 + (lane & 15);
    int c = (kcb & 1) * 32 + (lane >> 4) * 8 + j;
    int k = kcb >> 1;
    float v = (oc < NOC) ? src[((size_t)oc * 64 + c) * TS + k] : 0.f;
    dst[idx] = f2b(v);
}

// ---- NCHW fp32 -> NHWC bf16 transpose ----
template<int H, int W>
__global__ __launch_bounds__(256) void nchw2nhwc_bf16(const float* __restrict__ src,
                                                      u16* __restrict__ dst) {
    const int SEG = W / 64, HW = H * W;
    int blk = blockIdx.x;                  // B*H*SEG
    int b = blk / (H * SEG);
    int r = blk - b * (H * SEG);
    int h = r / SEG;
    int x0 = (r - h * SEG) * 64;
    int t = threadIdx.x;
    __shared__ float lds[64][65];
    const float* sb = src + (size_t)b * 64 * HW + (size_t)h * W + x0;
    int px = t & 63, cg = t >> 6;
#pragma unroll
    for (int i = 0; i < 16; ++i) {
        int c = cg * 16 + i;
        lds[c][px] = sb[(size_t)c * HW + px];
    }
    __syncthreads();
    u16* db = dst + ((size_t)b * HW + (size_t)h * W + x0) * 64;
    int c = t & 63, pg = t >> 6;
#pragma unroll
    for (int i = 0; i < 16; ++i) {
        int p = pg * 16 + i;
        db[(size_t)p * 64 + c] = f2b(lds[c][p]);
    }
}

// ---- bilinear 2x upsample: NCHW fp32 (192^2) -> NHWC bf16 (384^2) ----
__global__ __launch_bounds__(256) void upsample_nhwc_bf16(const float* __restrict__ src,
                                                          u16* __restrict__ dst) {
    const int Hh = 192, Wh = 192, H = 384, W = 384;
    int ox0 = blockIdx.x * 32;
    int oy  = blockIdx.y;
    int b   = blockIdx.z;
    int t = threadIdx.x;
    int iy  = oy >> 1;
    int oy2 = (oy & 1) ? min(iy + 1, Hh - 1) : max(iy - 1, 0);
    int ix0m1 = ox0 / 2 - 1;
    __shared__ float lds[2][64][19];
    const float* sb = src + (size_t)b * 64 * Hh * Wh;
    for (int idx = t; idx < 2 * 64 * 18; idx += 256) {
        int r2 = idx / (64 * 18);
        int rem = idx - r2 * (64 * 18);
        int c = rem / 18;
        int p = rem - c * 18;
        int gx = min(max(ix0m1 + p, 0), Wh - 1);
        int gy = r2 ? oy2 : iy;
        lds[r2][c][p] = sb[((size_t)c * Hh + gy) * Wh + gx];
    }
    __syncthreads();
    int c = t & 63, j = t >> 6;
    u16* db = dst + ((size_t)b * H * W + (size_t)oy * W + ox0) * 64;
#pragma unroll
    for (int ii = 0; ii < 8; ++ii) {
        int opx = j * 8 + ii;
        int ox = ox0 + opx;
        int ix = ox >> 1;
        int oxn = (ox & 1) ? min(ix + 1, Wh - 1) : max(ix - 1, 0);
        int il = ix - ix0m1;
        int ol = oxn - ix0m1;
        float cc = lds[0][c][il], cn = lds[0][c][ol];
        float nc = lds[1][c][il], nn = lds[1][c][ol];
        db[(size_t)opx * 64 + c] = f2b(0.5625f * cc + 0.1875f * (cn + nc) + 0.0625f * nn);
    }
}

// ---- conv3x3 offset conv, bf16 NHWC in, fragment weights, zero-pad ----
template<int H, int W>
__global__ __launch_bounds__(256, 4) void conv_off_rA(
    const u16*  __restrict__ srcT,   // B x HW x 64 bf16
    const u16*  __restrict__ wf,     // [18][2][64][8] bf16 fragments
    const float* __restrict__ bias,  // 27
    float* __restrict__ dst)         // B x 27 x H x W
{
    const int HW = H * W, SEGS = W / 16;
    int t = threadIdx.x;
    int wv = t >> 6, lane = t & 63, m16 = t & 15, quad = (t >> 4) & 3;
    int seg = blockIdx.x * 4 + wv;
    int b = seg / (H * SEGS);
    int r = seg - b * (H * SEGS);
    int h = r / SEGS;
    int x0 = (r - h * SEGS) * 16;

    const u16* sb = srcT + (size_t)b * HW * 64;
    float bz0 = bias[m16];
    float bz1 = (m16 < 11) ? bias[16 + m16] : 0.f;
    f32x4 acc[2] = {{bz0,bz0,bz0,bz0},{bz1,bz1,bz1,bz1}};

#pragma unroll
    for (int k = 0; k < 9; ++k) {
        const int ki = k / 3, kj = k % 3;
        int yy = h - 1 + ki;
        int xx = x0 + m16 - 1 + kj;
        bool ok = (yy >= 0 && yy < H && xx >= 0 && xx < W);
        int yc = min(max(yy, 0), H - 1);
        int xc = min(max(xx, 0), W - 1);
        const u16* base = sb + (size_t)(yc * W + xc) * 64 + quad * 8;
#pragma unroll
        for (int cb = 0; cb < 2; ++cb) {
            u32x4 raw = *(const u32x4*)(base + cb * 32);
            union { unsigned u[4]; bf16x8 v; } A;
#pragma unroll
            for (int q = 0; q < 4; ++q) A.u[q] = ok ? raw[q] : 0u;
            const u16* wrow = wf + (size_t)((k * 2 + cb) * 2) * 512 + lane * 8;
#pragma unroll
            for (int g = 0; g < 2; ++g) {
                bf16x8 bv = *(const bf16x8*)(wrow + g * 512);
                acc[g] = __builtin_amdgcn_mfma_f32_16x16x32_bf16(A.v, bv, acc[g], 0, 0, 0);
            }
        }
    }

    int xs = x0 + quad * 4;
    float* dbase = dst + (size_t)b * 27 * HW + (size_t)h * W + xs;
    *(f32x4*)(dbase + (size_t)m16 * HW) = acc[0];
    if (m16 < 11) *(f32x4*)(dbase + (size_t)(16 + m16) * HW) = acc[1];
}

// ---- conv1x1 residual as MFMA, bf16 NHWC in -> NHWC fp32 out ----
__global__ __launch_bounds__(256) void conv1x1_rA(
    const u16*  __restrict__ srcT,   // B x 36864 x 64 bf16
    const u16*  __restrict__ wf,     // [2][4][64][8]
    const float* __restrict__ rb,    // 64
    float* __restrict__ resT)        // B x 36864 x 64 fp32 NHWC
{
    const int H = 192, W = 192, HW = H * W, SEGS = W / 16;
    int t = threadIdx.x;
    int wv = t >> 6, lane = t & 63, m16 = t & 15, quad = (t >> 4) & 3;
    int seg = blockIdx.x * 4 + wv;
    int b = seg / (H * SEGS);
    int r = seg - b * (H * SEGS);
    int h = r / SEGS;
    int x0 = (r - h * SEGS) * 16;

    const u16* base = srcT + ((size_t)b * HW + (size_t)h * W + x0 + m16) * 64 + quad * 8;
    f32x4 acc[4];
#pragma unroll
    for (int g = 0; g < 4; ++g) { float bz = rb[g * 16 + m16]; acc[g] = {bz,bz,bz,bz}; }

#pragma unroll
    for (int cb = 0; cb < 2; ++cb) {
        bf16x8 A = *(const bf16x8*)(base + cb * 32);
        const u16* wrow = wf + (size_t)(cb * 4) * 512 + lane * 8;
#pragma unroll
        for (int g = 0; g < 4; ++g) {
            bf16x8 bv = *(const bf16x8*)(wrow + g * 512);
            acc[g] = __builtin_amdgcn_mfma_f32_16x16x32_bf16(A, bv, acc[g], 0, 0, 0);
        }
    }

    int xs = x0 + quad * 4;
    float* ob = resT + ((size_t)b * HW + (size_t)h * W) * 64;
#pragma unroll
    for (int g = 0; g < 4; ++g) {
        int oc = g * 16 + m16;
#pragma unroll
        for (int rg = 0; rg < 4; ++rg)
            ob[(size_t)(xs + rg) * 64 + oc] = acc[g][rg];
    }
}

// ---- deformable conv v2: bf16 NHWC gathers, fragment weights, full k-unroll ----
template<int H, int W, bool ADD_RES>
__global__ __launch_bounds__(256, 4) void dcn_rA(
    const u16*  __restrict__ srcT,   // B x HW x 64 bf16
    const float* __restrict__ off,   // B x 27 x H x W fp32
    const u16*  __restrict__ wf,     // [18][4][64][8]
    const float* __restrict__ bias,  // 64
    const float* __restrict__ resT,  // B x (H/2*W/2) x 64 fp32 NHWC (if ADD_RES)
    float* __restrict__ dst)         // B x 64 x H x W fp32 NCHW
{
    const int HW = H * W, SEGS = W / 16;
    int t = threadIdx.x;
    int wv = t >> 6, lane = t & 63, m16 = t & 15, quad = (t >> 4) & 3;
    int seg = blockIdx.x * 4 + wv;
    int b = seg / (H * SEGS);
    int r = seg - b * (H * SEGS);
    int h = r / SEGS;
    int x0 = (r - h * SEGS) * 16;

    const u16* sb = srcT + (size_t)b * HW * 64;
    const float* offp = off + (size_t)b * 27 * HW + (size_t)h * W + x0 + m16;

    // preload all 27 offset values into registers (one vmem burst)
    float dyv[9], dxv[9], msv[9];
#pragma unroll
    for (int k = 0; k < 9; ++k) {
        dyv[k] = offp[(size_t)(2 * k) * HW];
        dxv[k] = offp[(size_t)(2 * k + 1) * HW];
        msv[k] = offp[(size_t)(18 + k) * HW];
    }

    f32x4 acc[4];
#pragma unroll
    for (int g = 0; g < 4; ++g) { float bz = bias[g * 16 + m16]; acc[g] = {bz,bz,bz,bz}; }

#pragma unroll
    for (int k = 0; k < 9; ++k) {
        const int ki = k / 3, kj = k % 3;
        float mm = 1.f / (1.f + __expf(-msv[k]));
        float yf = (float)(h - 1 + ki) + dyv[k];
        float xf = (float)(x0 + m16 - 1 + kj) + dxv[k];
        float y0f = floorf(yf), x0f = floorf(xf);
        float wy = yf - y0f, wx = xf - x0f;
        int yi = (int)y0f, xi = (int)x0f;
        float vy0 = (yi >= 0 && yi < H) ? 1.f : 0.f;
        float vy1 = (yi + 1 >= 0 && yi + 1 < H) ? 1.f : 0.f;
        float vx0 = (xi >= 0 && xi < W) ? 1.f : 0.f;
        float vx1 = (xi + 1 >= 0 && xi + 1 < W) ? 1.f : 0.f;
        float w00 = (1.f - wy) * (1.f - wx) * vy0 * vx0 * mm;
        float w01 = (1.f - wy) * wx * vy0 * vx1 * mm;
        float w10 = wy * (1.f - wx) * vy1 * vx0 * mm;
        float w11 = wy * wx * vy1 * vx1 * mm;
        int y0c = min(max(yi, 0), H - 1), y1c = min(max(yi + 1, 0), H - 1);
        int x0c = min(max(xi, 0), W - 1), x1c = min(max(xi + 1, 0), W - 1);
        const u16* p00 = sb + (size_t)(y0c * W + x0c) * 64 + quad * 8;
        const u16* p01 = sb + (size_t)(y0c * W + x1c) * 64 + quad * 8;
        const u16* p10 = sb + (size_t)(y1c * W + x0c) * 64 + quad * 8;
        const u16* p11 = sb + (size_t)(y1c * W + x1c) * 64 + quad * 8;

#pragma unroll
        for (int cb = 0; cb < 2; ++cb) {
            u32x4 r00 = *(const u32x4*)(p00 + cb * 32);
            u32x4 r01 = *(const u32x4*)(p01 + cb * 32);
            u32x4 r10 = *(const u32x4*)(p10 + cb * 32);
            u32x4 r11 = *(const u32x4*)(p11 + cb * 32);
            union { unsigned u[4]; bf16x8 v; } A;
#pragma unroll
            for (int q = 0; q < 4; ++q) {
                float a0, a1, b0, b1, c0, c1, d0, d1;
                bpair(r00[q], a0, a1); bpair(r01[q], b0, b1);
                bpair(r10[q], c0, c1); bpair(r11[q], d0, d1);
                float e = fmaf(a0, w00, fmaf(b0, w01, fmaf(c0, w10, d0 * w11)));
                float o = fmaf(a1, w00, fmaf(b1, w01, fmaf(c1, w10, d1 * w11)));
                A.u[q] = pack2(e, o);
            }
            const u16* wrow = wf + (size_t)((k * 2 + cb) * 4) * 512 + lane * 8;
#pragma unroll
            for (int g = 0; g < 4; ++g) {
                bf16x8 bv = *(const bf16x8*)(wrow + g * 512);
                acc[g] = __builtin_amdgcn_mfma_f32_16x16x32_bf16(A.v, bv, acc[g], 0, 0, 0);
            }
        }
    }

    // epilogue: ELU (+ NHWC residual) + NCHW f32x4 stores
    int xs = x0 + quad * 4;
    float* dbase = dst + (size_t)b * 64 * HW + (size_t)h * W + xs;
    const int Hh = H / 2, Wh = W / 2;
    int iy = h >> 1;
    int oyn = (h & 1) ? min(iy + 1, Hh - 1) : max(iy - 1, 0);
    const float* rb0 = ADD_RES ? resT + ((size_t)b * Hh * Wh + (size_t)iy * Wh) * 64 : nullptr;
    const float* rb1 = ADD_RES ? resT + ((size_t)b * Hh * Wh + (size_t)oyn * Wh) * 64 : nullptr;
#pragma unroll
    for (int g = 0; g < 4; ++g) {
        int oc = g * 16 + m16;
        f32x4 v = acc[g];
#pragma unroll
        for (int rg = 0; rg < 4; ++rg) {
            float val = v[rg];
            val = val > 0.f ? val : (expf(val) - 1.f);
            if (ADD_RES) {
                int xq = xs + rg;
                int ix = xq >> 1;
                int oxn = (xq & 1) ? min(ix + 1, Wh - 1) : max(ix - 1, 0);
                val += 0.5625f * rb0[(size_t)ix * 64 + oc]
                     + 0.1875f * (rb0[(size_t)oxn * 64 + oc] + rb1[(size_t)ix * 64 + oc])
                     + 0.0625f * rb1[(size_t)oxn * 64 + oc];
            }
            v[rg] = val;
        }
        *(f32x4*)(dbase + (size_t)oc * HW) = v;
    }
}

extern "C" void kernel_launch(void* const* d_in, const int* in_sizes, int n_in,
                              void* d_out, int out_size, void* d_ws, size_t ws_size,
                              hipStream_t stream) {
    const float* x   = (const float*)d_in[0];
    const float* ow1 = (const float*)d_in[1];
    const float* ob1 = (const float*)d_in[2];
    const float* w1  = (const float*)d_in[3];
    const float* b1  = (const float*)d_in[4];
    const float* ow2 = (const float*)d_in[5];
    const float* ob2 = (const float*)d_in[6];
    const float* w2  = (const float*)d_in[7];
    const float* b2  = (const float*)d_in[8];
    const float* rw  = (const float*)d_in[9];
    const float* rbv = (const float*)d_in[10];
    float* out = (float*)d_out;

    // workspace layout — ~125 MB total (< proven 146 MiB)
    float* ws   = (float*)d_ws;
    float* off1 = ws;                       // 2*27*192*192 = 1,990,656 f
    float* h1   = off1 + 1990656;           // 2*64*192*192 = 4,718,592 f (NCHW fp32)
    float* r    = h1   + 4718592;           // 4,718,592 f (NHWC fp32, half-res)
    float* off2 = r    + 4718592;           // 2*27*384*384 = 7,962,624 f
    u16* xbh    = (u16*)(off2 + 7962624);   // 4,718,592 u16 (NHWC bf16 x)
    u16* u      = xbh + 4718592;            // 18,874,368 u16 (NHWC bf16 upsampled)
    u16* wfd1   = u + 18874368;             // 18*4*512 = 36,864
    u16* wfd2   = wfd1 + 36864;             // 36,864
    u16* wfo1   = wfd2 + 36864;             // 18*2*512 = 18,432
    u16* wfo2   = wfo1 + 18432;             // 18,432
    u16* wf11   = wfo2 + 18432;             // 2*4*512 = 4,096

    prep_frag<<<144, 256, 0, stream>>>(w1,  wfd1, 4, 18, 64, 9);
    prep_frag<<<144, 256, 0, stream>>>(w2,  wfd2, 4, 18, 64, 9);
    prep_frag<<< 72, 256, 0, stream>>>(ow1, wfo1, 2, 18, 27, 9);
    prep_frag<<< 72, 256, 0, stream>>>(ow2, wfo2, 2, 18, 27, 9);
    prep_frag<<< 16, 256, 0, stream>>>(rw,  wf11, 4,  2, 64, 1);

    nchw2nhwc_bf16<192, 192><<<2 * 192 * 3, 256, 0, stream>>>(x, xbh);
    conv_off_rA<192, 192><<<(2 * 192 * 12) / 4, 256, 0, stream>>>(xbh, wfo1, ob1, off1);
    conv1x1_rA<<<(2 * 192 * 12) / 4, 256, 0, stream>>>(xbh, wf11, rbv, r);
    dcn_rA<192, 192, false><<<(2 * 192 * 12) / 4, 256, 0, stream>>>(xbh, off1, wfd1, b1, nullptr, h1);
    upsample_nhwc_bf16<<<dim3(12, 384, 2), 256, 0, stream>>>(h1, u);
    conv_off_rA<384, 384><<<(2 * 384 * 24) / 4, 256, 0, stream>>>(u, wfo2, ob2, off2);
    dcn_rA<384, 384, true><<<(2 * 384 * 24) / 4, 256, 0, stream>>>(u, off2, wfd2, b2, r, out);
}